// Round 7
// baseline (162.245 us; speedup 1.0000x reference)
//
#include <hip/hip_runtime.h>

#define IN_F    4096
#define OUT_F   4096
#define K_DIM   4096
#define NNZ_C   838860
#define BATCH   512
#define BK      32
#define BM      128
#define BN      128

typedef short bf16x8 __attribute__((ext_vector_type(8)));
typedef float f32x4  __attribute__((ext_vector_type(4)));

__device__ __forceinline__ unsigned short f2bf(float f) {  // RNE fp32->bf16
    unsigned u = __float_as_uint(f);
    u += 0x7fffu + ((u >> 16) & 1u);
    return (unsigned short)(u >> 16);
}
__device__ __forceinline__ void gload_lds16(const void* g, void* l) {
    __builtin_amdgcn_global_load_lds(
        (const __attribute__((address_space(1))) unsigned int*)g,
        (__attribute__((address_space(3))) unsigned int*)l, 16, 0, 0);
}

// ---------------------------------------------------------------------------
// R13 node plan (4 -> 3 nodes; ~10 us/node measured gap R12):
//   1. hipMemsetAsync(W, 0)          -- graph-capturable (harness uses it)
//   2. scatcvt                       -- scatter + x-cvt + out=bias seed
//   3. gemm_at                       -- all SK splits atomicAdd f32 into out
// reduce_parts and the parts buffer are GONE.
// ---------------------------------------------------------------------------

// ---------------------------------------------------------------------------
// K2 "scatcvt": COO scatter-add (fire-and-forget packed-bf16 atomics, exact
// duplicate handling) + x fp32->bf16 cvt + out=bias seed, one dispatch.
// R9/R10: scatter is atomic-pipe-bound (~19 G random atomic/s, occupancy-
// invariant); cvt (13 MB) and bias-seed (8.4 MB) ride along ~free.
// Bias-seed MUST be in this kernel (kernel boundary orders it before the
// gemm's atomics -- no fences needed, R8 lesson).
// ---------------------------------------------------------------------------
#define N_CVT   (BATCH * K_DIM / 8)      // 262144 bf16x8 outputs
#define N_OUT   (BATCH * OUT_F / 4)      // 524288 float4 stores
#define NS_BLK  ((NNZ_C / 4 + 255) / 256)   // 820 scatter blocks
#define NC_BLK  (N_CVT / 256)               // 1024 cvt blocks
#define NB_BLK  (N_OUT / 256)               // 2048 bias blocks
__global__ void scatcvt(const int* __restrict__ row_idx,
                        const int* __restrict__ col_idx,
                        const float* __restrict__ values,
                        unsigned short* __restrict__ W,
                        const float* __restrict__ x,
                        unsigned short* __restrict__ xb,
                        const float* __restrict__ bias,
                        float* __restrict__ out) {
    int b = blockIdx.x;
    if (b < NS_BLK) {
        int i = b * 256 + threadIdx.x;           // NNZ_C/4 = 209715 entries
        if (i >= NNZ_C / 4) return;
        int4   r4 = ((const int4*)row_idx)[i];
        int4   c4 = ((const int4*)col_idx)[i];
        float4 v4 = ((const float4*)values)[i];
#pragma unroll
        for (int j = 0; j < 4; ++j) {
            int r = (&r4.x)[j], c = (&c4.x)[j];
            float v = (&v4.x)[j];
            unsigned idx = (unsigned)r * K_DIM + (unsigned)c;
            unsigned short h = f2bf(v);
            unsigned data = (idx & 1u) ? ((unsigned)h << 16) : (unsigned)h;
            unsigned long long addr = (unsigned long long)(W + (idx & ~1u));
            asm volatile("global_atomic_pk_add_bf16 %0, %1, off"
                         :: "v"(addr), "v"(data) : "memory");
        }
        return;
    }
    b -= NS_BLK;
    if (b < NC_BLK) {
        int i = b * 256 + threadIdx.x;
        const float4* p = (const float4*)x + (size_t)i * 2;
        float4 a = p[0], bb = p[1];
        union { unsigned short h[8]; bf16x8 v; } u;
        u.h[0] = f2bf(a.x);  u.h[1] = f2bf(a.y);  u.h[2] = f2bf(a.z);  u.h[3] = f2bf(a.w);
        u.h[4] = f2bf(bb.x); u.h[5] = f2bf(bb.y); u.h[6] = f2bf(bb.z); u.h[7] = f2bf(bb.w);
        ((bf16x8*)xb)[i] = u.v;
        return;
    }
    b -= NC_BLK;                                  // out = bias seed
    int i = b * 256 + threadIdx.x;
    if (i < N_OUT) {
        float4 bb = ((const float4*)bias)[i & (OUT_F / 4 - 1)];
        ((float4*)out)[i] = bb;
    }
}

// ---------------------------------------------------------------------------
// K3 "gemm_at": bf16 GEMM, B^T layout, 128x128 tile, SK=4 split-K,
// 512-thread 8-wave blocks (512 blocks = 2/CU x 8 waves = 16 waves/CU,
// R12's verified geometry). K-loop: R9's two-plane BK=64 __syncthreads
// structure (best measured; counted-vmcnt R10/R11 null at this shape).
// XOR staging/read swizzle verbatim (rule 21). Epilogue: COALESCED f32
// atomicAdd into bias-seeded out -- 16 lanes hit one 64B line, distinct
// addresses (no contention; unlike the scatter's random-4B 19G/s floor).
// Eliminates the parts buffer + reduce kernel + one graph node.
// ---------------------------------------------------------------------------
template <int SK>
__global__ void __launch_bounds__(512)
gemm_at(const unsigned short* __restrict__ Abf,   // [512][4096] bf16
        const unsigned short* __restrict__ Wbf,   // [4096][4096] bf16
        float* __restrict__ out) {                // [512][4096] f32, = bias
    __shared__ __align__(16) unsigned short As[2][BM * BK];   // 2 planes x 8 KB
    __shared__ __align__(16) unsigned short Bs[2][BN * BK];   // 2 planes x 8 KB

    const int nt = blockIdx.x, mt = blockIdx.y, s = blockIdx.z;
    const int t = threadIdx.x, w = t >> 6, ln = t & 63;   // w = 0..7
    const int wm = w & 1, wn = w >> 1;                    // 2 x 4 wave grid
    const int KSs = K_DIM / SK;                           // 1024 at SK=4
    const int ks0 = s * KSs;

    // staging: lane ln -> LDS row (ln>>2), physical chunk (ln&3);
    // global source = logical chunk (ln&3) ^ ((ln>>3)&3)   [measured: 0 conflicts]
    // wave w stages rows [w*16, w*16+16) of A and of B (8 waves cover 128).
    const int srow = w * 16 + (ln >> 2);
    const int scol = (((ln & 3) ^ ((ln >> 3) & 3)) * 8);
    const unsigned short* gA0 = Abf + (size_t)(mt * BM + srow) * K_DIM + ks0 + scol;
    const unsigned short* gB0 = Wbf + (size_t)(nt * BN + srow) * K_DIM + ks0 + scol;
    const int lA0o = (w * 16) * BK;          // LDS dest offset (wave-uniform)

    // read: logical quad q -> physical chunk q ^ ((lanem>>1)&3)
    const int quad = ln >> 4, lanem = ln & 15;
    const int rsw = (quad ^ ((lanem >> 1) & 3)) * 8;
    const int rAo = (wm * 64 + lanem) * BK + rsw;    // 64-row half
    const int rBo = (wn * 32 + lanem) * BK + rsw;    // 32-col quarter

    f32x4 acc[4][2];
#pragma unroll
    for (int mi = 0; mi < 4; ++mi)
#pragma unroll
        for (int ni = 0; ni < 2; ++ni)
            acc[mi][ni] = (f32x4){0.f, 0.f, 0.f, 0.f};

    // stage one 64-wide K-tile = two BK=32 planes (4 x global_load_lds x16B)
    auto stage = [&](int kt) {
#pragma unroll
        for (int ks = 0; ks < 2; ++ks) {
            const int off = kt * 64 + ks * BK;
            gload_lds16(gA0 + off, &As[ks][lA0o]);
            gload_lds16(gB0 + off, &Bs[ks][lA0o]);
        }
    };

    const int NK = KSs / 64;                 // 16 at SK=4
    stage(0);
    for (int kt = 0; kt < NK; ++kt) {
        __syncthreads();                     // drains vmcnt(0): tile staged
#pragma unroll
        for (int ks = 0; ks < 2; ++ks) {
            const unsigned short* rA = &As[ks][0] + rAo;
            const unsigned short* rB = &Bs[ks][0] + rBo;
            bf16x8 af[4], bfr[2];
#pragma unroll
            for (int mi = 0; mi < 4; ++mi) af[mi]  = *(const bf16x8*)(rA + mi * 16 * BK);
#pragma unroll
            for (int ni = 0; ni < 2; ++ni) bfr[ni] = *(const bf16x8*)(rB + ni * 16 * BK);
#pragma unroll
            for (int mi = 0; mi < 4; ++mi)
#pragma unroll
                for (int ni = 0; ni < 2; ++ni)
                    acc[mi][ni] = __builtin_amdgcn_mfma_f32_16x16x32_bf16(
                        af[mi], bfr[ni], acc[mi][ni], 0, 0, 0);
        }
        __syncthreads();                     // all waves done reading planes
        if (kt + 1 < NK) stage(kt + 1);      // safe: buffer free; completion
    }                                        // enforced by next first barrier

    // C/D layout: col = lanem, row = quad*4 + r; 16 lanes = one 64B segment.
    // Coalesced atomic f32 adds into bias-seeded out.
    const int row0 = mt * BM + wm * 64 + quad * 4;
    const int col0 = nt * BN + wn * 32 + lanem;
#pragma unroll
    for (int mi = 0; mi < 4; ++mi)
#pragma unroll
        for (int ni = 0; ni < 2; ++ni)
#pragma unroll
            for (int r = 0; r < 4; ++r)
                atomicAdd(&out[(size_t)(row0 + mi * 16 + r) * OUT_F + col0 + ni * 16],
                          acc[mi][ni][r]);
}

// ---------------------------------------------------------------------------
// ws: xb 4.19 | W 33.55  -> 37.75 MB
// ---------------------------------------------------------------------------
extern "C" void kernel_launch(void* const* d_in, const int* in_sizes, int n_in,
                              void* d_out, int out_size, void* d_ws, size_t ws_size,
                              hipStream_t stream) {
    const float* x       = (const float*)d_in[0];
    const int*   row_idx = (const int*)d_in[1];
    const int*   col_idx = (const int*)d_in[2];
    const float* values  = (const float*)d_in[3];
    const float* bias    = (const float*)d_in[4];
    float*       out     = (float*)d_out;

    unsigned short* xb = (unsigned short*)d_ws;
    unsigned short* W  = xb + (size_t)BATCH * K_DIM;

    // node 1: zero W (DMA memset node; graph-capturable -- harness's own
    // reset() enqueues hipMemsetAsync). Must fully precede scatter atomics.
    hipMemsetAsync(W, 0, (size_t)OUT_F * K_DIM * 2, stream);

    // node 2: scatter + cvt + bias-seed
    scatcvt<<<NS_BLK + NC_BLK + NB_BLK, 256, 0, stream>>>(
        row_idx, col_idx, values, W, x, xb, bias, out);

    // node 3: GEMM with coalesced-atomic split-K epilogue
    gemm_at<4><<<dim3(OUT_F / BN, BATCH / BM, 4), 512, 0, stream>>>(xb, W, out);
}

// Round 8
// 147.437 us; speedup vs baseline: 1.1004x; 1.1004x over previous
//
#include <hip/hip_runtime.h>

#define IN_F    4096
#define OUT_F   4096
#define K_DIM   4096
#define NNZ_C   838860
#define BATCH   512
#define BK      32
#define BM      128
#define BN      128

typedef short bf16x8 __attribute__((ext_vector_type(8)));
typedef float f32x4  __attribute__((ext_vector_type(4)));

__device__ __forceinline__ unsigned short f2bf(float f) {  // RNE fp32->bf16
    unsigned u = __float_as_uint(f);
    u += 0x7fffu + ((u >> 16) & 1u);
    return (unsigned short)(u >> 16);
}
__device__ __forceinline__ void gload_lds16(const void* g, void* l) {
    __builtin_amdgcn_global_load_lds(
        (const __attribute__((address_space(1))) unsigned int*)g,
        (__attribute__((address_space(3))) unsigned int*)l, 16, 0, 0);
}

// ---------------------------------------------------------------------------
// K1 "zero_w": zero the dense W buffer (must fully precede the scatter).
// 33.5 MB write-only ~= 7 us. Kernel (not memset): R13's memset variant was
// part of a 15 us regression; kernel form is the measured-good baseline.
// ---------------------------------------------------------------------------
#define N_WZ   (OUT_F * K_DIM / 8)       // 2097152 uint4 stores
__global__ void zero_w(uint4* __restrict__ Wz) {
    int i = blockIdx.x * 256 + threadIdx.x;
    Wz[i] = make_uint4(0, 0, 0, 0);
}
#define ZW_BLOCKS (N_WZ / 256)           // 8192

// ---------------------------------------------------------------------------
// K2 "scatcvt": COO scatter-add (fire-and-forget packed-bf16 atomics, exact
// duplicate handling) + x fp32->bf16 conversion in the SAME dispatch.
// R9/R10: scatter is atomic-pipe-bound (~19 G random atomic/s, occupancy-
// invariant); the cvt's 13 MB rides along ~free. Fallback path seeds out=bias.
// ---------------------------------------------------------------------------
#define N_CVT   (BATCH * K_DIM / 8)      // 262144 bf16x8 outputs
#define N_OUT   (BATCH * OUT_F / 4)      // 524288 float4 stores (fallback)
#define NS_BLK  ((NNZ_C / 4 + 255) / 256)   // 820 scatter blocks
#define NC_BLK  (N_CVT / 256)               // 1024 cvt blocks
#define NB_BLK  (N_OUT / 256)               // 2048 bias blocks (fallback only)
__global__ void scatcvt(const int* __restrict__ row_idx,
                        const int* __restrict__ col_idx,
                        const float* __restrict__ values,
                        unsigned short* __restrict__ W,
                        const float* __restrict__ x,
                        unsigned short* __restrict__ xb,
                        const float* __restrict__ bias,
                        float* __restrict__ out) {
    int b = blockIdx.x;
    if (b < NS_BLK) {
        int i = b * 256 + threadIdx.x;           // NNZ_C/4 = 209715 entries
        if (i >= NNZ_C / 4) return;
        int4   r4 = ((const int4*)row_idx)[i];
        int4   c4 = ((const int4*)col_idx)[i];
        float4 v4 = ((const float4*)values)[i];
#pragma unroll
        for (int j = 0; j < 4; ++j) {
            int r = (&r4.x)[j], c = (&c4.x)[j];
            float v = (&v4.x)[j];
            unsigned idx = (unsigned)r * K_DIM + (unsigned)c;
            unsigned short h = f2bf(v);
            unsigned data = (idx & 1u) ? ((unsigned)h << 16) : (unsigned)h;
            unsigned long long addr = (unsigned long long)(W + (idx & ~1u));
            asm volatile("global_atomic_pk_add_bf16 %0, %1, off"
                         :: "v"(addr), "v"(data) : "memory");
        }
        return;
    }
    b -= NS_BLK;
    if (b < NC_BLK) {
        int i = b * 256 + threadIdx.x;
        const float4* p = (const float4*)x + (size_t)i * 2;
        float4 a = p[0], bb = p[1];
        union { unsigned short h[8]; bf16x8 v; } u;
        u.h[0] = f2bf(a.x);  u.h[1] = f2bf(a.y);  u.h[2] = f2bf(a.z);  u.h[3] = f2bf(a.w);
        u.h[4] = f2bf(bb.x); u.h[5] = f2bf(bb.y); u.h[6] = f2bf(bb.z); u.h[7] = f2bf(bb.w);
        ((bf16x8*)xb)[i] = u.v;
        return;
    }
    b -= NC_BLK;                                  // fallback-only bias seed
    int i = b * 256 + threadIdx.x;
    if (i < N_OUT) {
        float4 bb = ((const float4*)bias)[i & (OUT_F / 4 - 1)];
        ((float4*)out)[i] = bb;
    }
}

// ---------------------------------------------------------------------------
// K3: bf16 GEMM, B^T layout, 128x128 tile, SK=4, 512-thread 8-wave blocks
// (R12's verified geometry: 512 blocks = 2/CU x 8 waves = 16 waves/CU).
// K-loop: R9's two-plane BK=64 __syncthreads structure (best measured;
// counted-vmcnt R10/R11 null at this shape; atomic epilogue R13 regressed).
// XOR staging/read swizzle verbatim (rule 21).
// R14 (only change vs R12): XCD-aware 1D block decode -- each K-split s is
// pinned to one XCD PAIR (xcd = id&7; s = xcd>>1), so a given XCD's L2 sees
// one 8.4 MB W K-slice instead of all four (33.5 MB): L2 overcommit 8x->2x.
// Bijective: 512 = 8 xcds x 64; nt/mt decoded from id>>3. Per XCD: 64
// blocks = 2/CU on its 32 CUs (balanced). No sync/layout changes.
// Template: SK = split-K; EPI 0 = plain-store (s==0 -> out+bias, s>0 ->
// parts[s-1]); EPI 1 = atomicAdd fallback (out pre-seeded with bias).
// ---------------------------------------------------------------------------
template <int EPI, int SK>
__global__ void __launch_bounds__(512)
gemm_bt(const unsigned short* __restrict__ Abf,   // [512][4096] bf16
        const unsigned short* __restrict__ Wbf,   // [4096][4096] bf16
        const float* __restrict__ bias,
        float* __restrict__ out,                  // [512][4096] f32
        float* __restrict__ parts) {              // (SK-1) x [512][4096] f32
    __shared__ __align__(16) unsigned short As[2][BM * BK];   // 2 planes x 8 KB
    __shared__ __align__(16) unsigned short Bs[2][BN * BK];   // 2 planes x 8 KB

    // XCD-pinned decode (R14): id -> (nt, mt, s) with s = (id&7)>>1.
    const int id  = blockIdx.x;              // 0..511
    const int xcd = id & 7;
    const int ii  = id >> 3;                 // 0..63 within XCD
    const int s   = xcd >> 1;                // K-split pinned to XCD pair
    const int mt  = ((xcd & 1) << 1) | (ii & 1);   // 0..3
    const int nt  = ii >> 1;                 // 0..31

    const int t = threadIdx.x, w = t >> 6, ln = t & 63;   // w = 0..7
    const int wm = w & 1, wn = w >> 1;                    // 2 x 4 wave grid
    const int KSs = K_DIM / SK;                           // 1024 at SK=4
    const int ks0 = s * KSs;

    // staging: lane ln -> LDS row (ln>>2), physical chunk (ln&3);
    // global source = logical chunk (ln&3) ^ ((ln>>3)&3)   [measured: 0 conflicts]
    // wave w stages rows [w*16, w*16+16) of A and of B (8 waves cover 128).
    const int srow = w * 16 + (ln >> 2);
    const int scol = (((ln & 3) ^ ((ln >> 3) & 3)) * 8);
    const unsigned short* gA0 = Abf + (size_t)(mt * BM + srow) * K_DIM + ks0 + scol;
    const unsigned short* gB0 = Wbf + (size_t)(nt * BN + srow) * K_DIM + ks0 + scol;
    const int lA0o = (w * 16) * BK;          // LDS dest offset (wave-uniform)

    // read: logical quad q -> physical chunk q ^ ((lanem>>1)&3)
    const int quad = ln >> 4, lanem = ln & 15;
    const int rsw = (quad ^ ((lanem >> 1) & 3)) * 8;
    const int rAo = (wm * 64 + lanem) * BK + rsw;    // 64-row half
    const int rBo = (wn * 32 + lanem) * BK + rsw;    // 32-col quarter

    f32x4 acc[4][2];
#pragma unroll
    for (int mi = 0; mi < 4; ++mi)
#pragma unroll
        for (int ni = 0; ni < 2; ++ni)
            acc[mi][ni] = (f32x4){0.f, 0.f, 0.f, 0.f};

    // stage one 64-wide K-tile = two BK=32 planes (4 x global_load_lds x16B)
    auto stage = [&](int kt) {
#pragma unroll
        for (int ks = 0; ks < 2; ++ks) {
            const int off = kt * 64 + ks * BK;
            gload_lds16(gA0 + off, &As[ks][lA0o]);
            gload_lds16(gB0 + off, &Bs[ks][lA0o]);
        }
    };

    const int NK = KSs / 64;                 // 16 at SK=4
    stage(0);
    for (int kt = 0; kt < NK; ++kt) {
        __syncthreads();                     // drains vmcnt(0): tile staged
#pragma unroll
        for (int ks = 0; ks < 2; ++ks) {
            const unsigned short* rA = &As[ks][0] + rAo;
            const unsigned short* rB = &Bs[ks][0] + rBo;
            bf16x8 af[4], bfr[2];
#pragma unroll
            for (int mi = 0; mi < 4; ++mi) af[mi]  = *(const bf16x8*)(rA + mi * 16 * BK);
#pragma unroll
            for (int ni = 0; ni < 2; ++ni) bfr[ni] = *(const bf16x8*)(rB + ni * 16 * BK);
#pragma unroll
            for (int mi = 0; mi < 4; ++mi)
#pragma unroll
                for (int ni = 0; ni < 2; ++ni)
                    acc[mi][ni] = __builtin_amdgcn_mfma_f32_16x16x32_bf16(
                        af[mi], bfr[ni], acc[mi][ni], 0, 0, 0);
        }
        __syncthreads();                     // all waves done reading planes
        if (kt + 1 < NK) stage(kt + 1);      // safe: buffer free; completion
    }                                        // enforced by next first barrier

    // C/D layout: col = lanem, row = quad*4 + r; 16 lanes = one 64B segment.
    const int row0 = mt * BM + wm * 64 + quad * 4;
    const int col0 = nt * BN + wn * 32 + lanem;
    if (EPI == 0) {
        float bv[2];
#pragma unroll
        for (int ni = 0; ni < 2; ++ni) bv[ni] = (s == 0) ? bias[col0 + ni * 16] : 0.f;
        float* dst = (s == 0) ? out : parts + (size_t)(s - 1) * BATCH * OUT_F;
#pragma unroll
        for (int mi = 0; mi < 4; ++mi)
#pragma unroll
            for (int ni = 0; ni < 2; ++ni)
#pragma unroll
                for (int r = 0; r < 4; ++r)
                    dst[(size_t)(row0 + mi * 16 + r) * OUT_F + col0 + ni * 16] =
                        acc[mi][ni][r] + bv[ni];
    } else {
#pragma unroll
        for (int mi = 0; mi < 4; ++mi)
#pragma unroll
            for (int ni = 0; ni < 2; ++ni)
#pragma unroll
                for (int r = 0; r < 4; ++r)
                    atomicAdd(&out[(size_t)(row0 + mi * 16 + r) * OUT_F + col0 + ni * 16],
                              acc[mi][ni][r]);
    }
}

// ---------------------------------------------------------------------------
// K4: out += sum(parts[0..2])  (42 MB streamed, ~7 us). Separate kernel:
// kernel boundary is ONE cheap system flush. R8 (per-block fences) and R13
// (atomic-f32 epilogue) both measured worse. Do not re-fuse.
// ---------------------------------------------------------------------------
__global__ void reduce_parts(float* __restrict__ out,
                             const float* __restrict__ parts) {
    int i = blockIdx.x * 256 + threadIdx.x;          // 524288 float4s
    float4 a = ((const float4*)out)[i];
#pragma unroll
    for (int p = 0; p < 3; ++p) {
        float4 b = ((const float4*)(parts + (size_t)p * BATCH * OUT_F))[i];
        a.x += b.x; a.y += b.y; a.z += b.z; a.w += b.w;
    }
    ((float4*)out)[i] = a;
}

// ---------------------------------------------------------------------------
// ws: xb 4.19 | W 33.55 | parts 3 x 8.39 = 25.17  -> 62.9 MB (fallback if less)
// ---------------------------------------------------------------------------
extern "C" void kernel_launch(void* const* d_in, const int* in_sizes, int n_in,
                              void* d_out, int out_size, void* d_ws, size_t ws_size,
                              hipStream_t stream) {
    const float* x       = (const float*)d_in[0];
    const int*   row_idx = (const int*)d_in[1];
    const int*   col_idx = (const int*)d_in[2];
    const float* values  = (const float*)d_in[3];
    const float* bias    = (const float*)d_in[4];
    float*       out     = (float*)d_out;

    unsigned short* xb = (unsigned short*)d_ws;
    unsigned short* W  = xb + (size_t)BATCH * K_DIM;
    float* parts = (float*)(W + (size_t)OUT_F * K_DIM);
    size_t need = (size_t)BATCH * K_DIM * 2 + (size_t)OUT_F * K_DIM * 2
                + (size_t)3 * BATCH * OUT_F * 4;
    bool use_parts = (ws_size >= need);

    zero_w<<<ZW_BLOCKS, 256, 0, stream>>>((uint4*)W);

    int sc_blocks = NS_BLK + NC_BLK + (use_parts ? 0 : NB_BLK);
    scatcvt<<<sc_blocks, 256, 0, stream>>>(row_idx, col_idx, values, W,
                                           x, xb, bias, out);

    if (use_parts) {
        gemm_bt<0, 4><<<512, 512, 0, stream>>>(xb, W, bias, out, parts);
        reduce_parts<<<BATCH * OUT_F / 4 / 256, 256, 0, stream>>>(out, parts);
    } else {
        gemm_bt<1, 4><<<512, 512, 0, stream>>>(xb, W, bias, out, nullptr);
    }
}